// Round 1
// baseline (401.064 us; speedup 1.0000x reference)
//
#include <hip/hip_runtime.h>

// GCN link predictor: z1 = relu(GCNConv(x,W1,b1)); z2 = GCNConv(z1,W2,b2);
// out[e] = dot(z2[src[e]], z2[dst[e]])
// R9: full bf16 data plane (thr 2.07), bf16 MFMA GEMM w/ register-resident W.
// R10: scatter fixed — csr payload merged to int2 (one 8B store/edge), 4
//      edges/thread; deg 4 edges/thread; xbf pass dropped.
// R11: gemm was NOT register-resident (VGPR_Count=52 < 64 needed for W frags;
//      allocator targeting 8 waves/SIMD sank W loads into the s-loop -> L2
//      latency stall per 16-row step, MfmaUtil 4.4%). Fix:
//      __launch_bounds__(256,2) lifts VGPR cap; asm memory fence pins W loads
//      before the loop; 128 rows/block; static double-buffered A prefetch
//      (fully unrolled, compile-time buffer indices) hides A-load latency
//      under the MFMA chain.

typedef __attribute__((ext_vector_type(8))) short short8;  // 8 bf16 = 4 VGPRs
typedef __attribute__((ext_vector_type(4))) float f32x4;

__device__ __forceinline__ unsigned bf16_rne(float x) {
  unsigned u = __builtin_bit_cast(unsigned, x);
  return (u + 0x7FFFu + ((u >> 16) & 1u)) >> 16;
}
__device__ __forceinline__ float bf2f(unsigned short u) {
  return __builtin_bit_cast(float, ((unsigned)u) << 16);
}

// ---------- degree: 4 edges/thread ----------
__global__ __launch_bounds__(256) void deg_kernel(const int* __restrict__ dst,
                                                  int* __restrict__ deg, int E) {
  int base = blockIdx.x * 1024 + threadIdx.x;
#pragma unroll
  for (int i = 0; i < 4; ++i) {
    int e = base + i * 256;
    if (e < E) atomicAdd(&deg[dst[e]], 1);
  }
}

// ---------- block scan (512 elems/block) ----------
__global__ __launch_bounds__(512) void scan1_kernel(const int* __restrict__ in,
                                                    int* __restrict__ tmp,
                                                    int* __restrict__ bsums, int n) {
  __shared__ int sm[2][512];
  int t = threadIdx.x;
  int gid = blockIdx.x * 512 + t;
  int v = (gid < n) ? in[gid] : 0;
  int pp = 0;
  sm[0][t] = v;
  __syncthreads();
  for (int off = 1; off < 512; off <<= 1) {
    int nv = sm[pp][t];
    if (t >= off) nv += sm[pp][t - off];
    sm[pp ^ 1][t] = nv;
    pp ^= 1;
    __syncthreads();
  }
  int inc = sm[pp][t];
  if (gid < n) tmp[gid] = inc;
  if (t == 511) bsums[blockIdx.x] = inc;
}

__global__ __launch_bounds__(256) void scan2_kernel(int* bsums, int nb) {
  __shared__ int sm[2][256];
  int t = threadIdx.x;
  int v = (t < nb) ? bsums[t] : 0;
  int pp = 0;
  sm[0][t] = v;
  __syncthreads();
  for (int off = 1; off < 256; off <<= 1) {
    int nv = sm[pp][t];
    if (t >= off) nv += sm[pp][t - off];
    sm[pp ^ 1][t] = nv;
    pp ^= 1;
    __syncthreads();
  }
  int inc = sm[pp][t];
  if (t < nb) bsums[t] = inc - v;  // exclusive
}

// rowptr from scan, plus dinv = rsqrt(deg+1) fused here
__global__ __launch_bounds__(256) void scan3_kernel(const int* __restrict__ tmp,
                                                    const int* __restrict__ bsums,
                                                    const int* __restrict__ deg,
                                                    int* __restrict__ rowptr,
                                                    float* __restrict__ dinv, int n) {
  int gid = blockIdx.x * 256 + threadIdx.x;
  if (gid < n) {
    rowptr[gid + 1] = tmp[gid] + bsums[gid >> 9];
    dinv[gid] = rsqrtf((float)(deg[gid] + 1));  // +1 self loop
  }
  if (gid == 0) rowptr[0] = 0;
}

// CSR scatter: one int2 {src, eid} store per edge; 4 edges/thread for MLP.
__global__ __launch_bounds__(256) void scatter_kernel(const int* __restrict__ src,
                                                      const int* __restrict__ dst,
                                                      const int* __restrict__ rowptr,
                                                      int* __restrict__ cnt,
                                                      int2* __restrict__ csr, int E) {
  int base = blockIdx.x * 1024 + threadIdx.x;
#pragma unroll
  for (int i = 0; i < 4; ++i) {
    int e = base + i * 256;
    if (e < E) {
      int d = dst[e];
      int pos = rowptr[d] + atomicAdd(&cnt[d], 1);
      csr[pos] = make_int2(src[e], e);
    }
  }
}

// ---------- pack W[128][128] fp32 -> bf16 hi/lo in MFMA B-fragment order ----
// B frag (16x16x32): lane holds B[k=(lane>>4)*8+j][n=lane&15], j=0..7.
// Layout: Wp[half(0=hi,1=lo)][ct(8)][kf(4)][lane(64)][8] bf16.
__global__ __launch_bounds__(256) void wpack_kernel(const float* __restrict__ W,
                                                    short* __restrict__ Wp) {
  int t = blockIdx.x * 256 + threadIdx.x;  // 2048 = ct*256 + kf*64 + lane
  if (t >= 2048) return;
  int lane = t & 63;
  int kf = (t >> 6) & 3;
  int ct = t >> 8;
  int col = ct * 16 + (lane & 15);
  int k0 = kf * 32 + (lane >> 4) * 8;
  short* dh = Wp + ((((0 * 8 + ct) * 4 + kf) * 64) + lane) * 8;
  short* dl = Wp + ((((1 * 8 + ct) * 4 + kf) * 64) + lane) * 8;
  for (int j = 0; j < 8; ++j) {
    float w = W[(k0 + j) * 128 + col];
    unsigned h = bf16_rne(w);
    float hf = __builtin_bit_cast(float, h << 16);
    unsigned lo = bf16_rne(w - hf);
    dh[j] = (short)h;
    dl[j] = (short)lo;
  }
}

// ---------- bf16 MFMA GEMM: out[r,:] = bf16( dinv[r] * (A[r,:] @ W) ) ----
// FP32A=true: A is fp32, converted to bf16 in-register (layer 1, reads x).
// FP32A=false: A is bf16 (layer 2). W split hi/lo, register-resident.
// 128 rows/block, 4 waves, wave owns 2 col-tiles. No LDS, no syncs.
// __launch_bounds__(256,2): VGPR cap 256 so W frags (64 VGPRs) stay resident.
// Static double-buffered A prefetch: loads for step s+1 issue before MFMAs
// of step s (fully unrolled -> compile-time buffer indices, no scratch).
template <bool FP32A>
__global__ __launch_bounds__(256, 2) void gemm_kernel(const void* __restrict__ Av,
                                                      const short* __restrict__ Wp,
                                                      const float* __restrict__ dinv,
                                                      unsigned short* __restrict__ out,
                                                      int M) {
  const int wave = threadIdx.x >> 6;
  const int lane = threadIdx.x & 63;
  const int quad = lane >> 4;
  const int l15 = lane & 15;

  // W fragments for this wave's 2 col-tiles (hi+lo, 4 kfrags) -> 64 VGPRs
  short8 Bh[2][4], Bl[2][4];
  const short8* Wp8 = (const short8*)Wp;
#pragma unroll
  for (int c = 0; c < 2; ++c) {
    const int ct = wave * 2 + c;
#pragma unroll
    for (int f = 0; f < 4; ++f) {
      Bh[c][f] = Wp8[((0 * 8 + ct) * 4 + f) * 64 + lane];
      Bl[c][f] = Wp8[((1 * 8 + ct) * 4 + f) * 64 + lane];
    }
  }
  // Pin the W loads above this point — allocator must not sink them into
  // the row loop (that was the R10 52-VGPR latency bug).
  asm volatile("" ::: "memory");

  const int rb0 = blockIdx.x * 128;
  const int colbase = wave * 32 + l15;

  const float4 f4z = {0.f, 0.f, 0.f, 0.f};
  const short8 s8z = {0, 0, 0, 0, 0, 0, 0, 0};
  float4 rawf[2][8];  // fp32 A staging (layer 1)
  short8 rawb[2][4];  // bf16 A staging (layer 2)

  // prologue: stage step 0 into buffer 0
  {
    const int arow = rb0 + l15;
    const bool rok = arow < M;
    if constexpr (FP32A) {
      const float4* A4 = (const float4*)Av + (size_t)arow * 32;
#pragma unroll
      for (int u = 0; u < 8; ++u)
        rawf[0][u] = rok ? A4[(u >> 1) * 8 + quad * 2 + (u & 1)] : f4z;
    } else {
      const unsigned short* A2 = (const unsigned short*)Av + (size_t)arow * 128;
#pragma unroll
      for (int f = 0; f < 4; ++f)
        rawb[0][f] = rok ? *(const short8*)(A2 + f * 32 + quad * 8) : s8z;
    }
  }

#pragma unroll
  for (int s = 0; s < 8; ++s) {
    const int cur = s & 1;
    const int nxt = cur ^ 1;
    // issue next step's loads first — independent of current compute
    if (s < 7) {
      const int arow = rb0 + (s + 1) * 16 + l15;
      const bool rok = arow < M;
      if constexpr (FP32A) {
        const float4* A4 = (const float4*)Av + (size_t)arow * 32;
#pragma unroll
        for (int u = 0; u < 8; ++u)
          rawf[nxt][u] = rok ? A4[(u >> 1) * 8 + quad * 2 + (u & 1)] : f4z;
      } else {
        const unsigned short* A2 = (const unsigned short*)Av + (size_t)arow * 128;
#pragma unroll
        for (int f = 0; f < 4; ++f)
          rawb[nxt][f] = rok ? *(const short8*)(A2 + f * 32 + quad * 8) : s8z;
      }
    }

    // convert current buffer to bf16 A-frags: lane holds A[m=l15][k=f*32+quad*8+j]
    short8 af[4];
    if constexpr (FP32A) {
#pragma unroll
      for (int f = 0; f < 4; ++f) {
        const float4 a0 = rawf[cur][f * 2];
        const float4 a1 = rawf[cur][f * 2 + 1];
        const float av[8] = {a0.x, a0.y, a0.z, a0.w, a1.x, a1.y, a1.z, a1.w};
#pragma unroll
        for (int j = 0; j < 8; ++j) af[f][j] = (short)bf16_rne(av[j]);
      }
    } else {
#pragma unroll
      for (int f = 0; f < 4; ++f) af[f] = rawb[cur][f];
    }

    f32x4 acc0 = {0.f, 0.f, 0.f, 0.f};
    f32x4 acc1 = {0.f, 0.f, 0.f, 0.f};
#pragma unroll
    for (int f = 0; f < 4; ++f) {
      acc0 = __builtin_amdgcn_mfma_f32_16x16x32_bf16(af[f], Bh[0][f], acc0, 0, 0, 0);
      acc1 = __builtin_amdgcn_mfma_f32_16x16x32_bf16(af[f], Bh[1][f], acc1, 0, 0, 0);
      acc0 = __builtin_amdgcn_mfma_f32_16x16x32_bf16(af[f], Bl[0][f], acc0, 0, 0, 0);
      acc1 = __builtin_amdgcn_mfma_f32_16x16x32_bf16(af[f], Bl[1][f], acc1, 0, 0, 0);
    }

    // epilogue: C/D layout col=lane&15, row=quad*4+i
    const int rb = rb0 + s * 16;
#pragma unroll
    for (int i = 0; i < 4; ++i) {
      const int r = rb + quad * 4 + i;
      if (r < M) {
        const float d = dinv[r];
        out[(size_t)r * 128 + colbase] = (unsigned short)bf16_rne(acc0[i] * d);
        out[(size_t)r * 128 + colbase + 16] = (unsigned short)bf16_rne(acc1[i] * d);
      }
    }
  }
}

// ---------- aggregation over prescaled bf16 rows ----------
// out[i] = bf16( dinv[i]*(xw[i] + sum_j xw[j]) + b ), fp32 accumulation.
// 16 lanes/node, one ushort8 (16B) per lane per row, neighbor unroll x4.
__global__ __launch_bounds__(256) void agg_kernel(const unsigned short* __restrict__ xw,
                                                  const float* __restrict__ dinv,
                                                  const int* __restrict__ rowptr,
                                                  const int2* __restrict__ csr,
                                                  const float* __restrict__ bias,
                                                  unsigned short* __restrict__ out,
                                                  int relu, int N) {
  int node = blockIdx.x * 16 + (threadIdx.x >> 4);
  int l = threadIdx.x & 15;
  if (node >= N) return;
  const short8* xw8 = (const short8*)xw;  // row = 16 short8 groups
  short8 sv = xw8[(size_t)node * 16 + l];
  float acc[8];
#pragma unroll
  for (int j = 0; j < 8; ++j) acc[j] = bf2f((unsigned short)sv[j]);
  int s = rowptr[node], e = rowptr[node + 1];
  int k = s;
  for (; k + 4 <= e; k += 4) {
    int j0 = csr[k].x, j1 = csr[k + 1].x, j2 = csr[k + 2].x, j3 = csr[k + 3].x;
    short8 v0 = xw8[(size_t)j0 * 16 + l];
    short8 v1 = xw8[(size_t)j1 * 16 + l];
    short8 v2 = xw8[(size_t)j2 * 16 + l];
    short8 v3 = xw8[(size_t)j3 * 16 + l];
#pragma unroll
    for (int j = 0; j < 8; ++j) {
      acc[j] += (bf2f((unsigned short)v0[j]) + bf2f((unsigned short)v1[j])) +
                (bf2f((unsigned short)v2[j]) + bf2f((unsigned short)v3[j]));
    }
  }
  for (; k < e; ++k) {
    short8 v = xw8[(size_t)csr[k].x * 16 + l];
#pragma unroll
    for (int j = 0; j < 8; ++j) acc[j] += bf2f((unsigned short)v[j]);
  }
  float di = dinv[node];
  const float4* b4 = (const float4*)bias;
  float4 bb0 = b4[l * 2], bb1 = b4[l * 2 + 1];
  float bv[8] = {bb0.x, bb0.y, bb0.z, bb0.w, bb1.x, bb1.y, bb1.z, bb1.w};
  short8 o;
#pragma unroll
  for (int j = 0; j < 8; ++j) {
    float v = fmaf(di, acc[j], bv[j]);
    if (relu) v = fmaxf(v, 0.f);
    o[j] = (short)bf16_rne(v);
  }
  ((short8*)out)[(size_t)node * 16 + l] = o;
}

// ---------- decode over dst-CSR, bf16 z2: 16 lanes/node ----------
__global__ __launch_bounds__(256) void decode_kernel(const unsigned short* __restrict__ z,
                                                     const int* __restrict__ rowptr,
                                                     const int2* __restrict__ csr,
                                                     float* __restrict__ out, int N) {
  int node = blockIdx.x * 16 + (threadIdx.x >> 4);
  int l = threadIdx.x & 15;
  if (node >= N) return;
  const short8* z8 = (const short8*)z;
  short8 zv = z8[(size_t)node * 16 + l];
  float zd[8];
#pragma unroll
  for (int j = 0; j < 8; ++j) zd[j] = bf2f((unsigned short)zv[j]);
  int s = rowptr[node], e = rowptr[node + 1];
  int k = s;
  for (; k + 4 <= e; k += 4) {
    int2 c0 = csr[k], c1 = csr[k + 1], c2 = csr[k + 2], c3 = csr[k + 3];
    short8 v0 = z8[(size_t)c0.x * 16 + l];
    short8 v1 = z8[(size_t)c1.x * 16 + l];
    short8 v2 = z8[(size_t)c2.x * 16 + l];
    short8 v3 = z8[(size_t)c3.x * 16 + l];
    float p0 = 0.f, p1 = 0.f, p2 = 0.f, p3 = 0.f;
#pragma unroll
    for (int j = 0; j < 8; ++j) {
      p0 = fmaf(zd[j], bf2f((unsigned short)v0[j]), p0);
      p1 = fmaf(zd[j], bf2f((unsigned short)v1[j]), p1);
      p2 = fmaf(zd[j], bf2f((unsigned short)v2[j]), p2);
      p3 = fmaf(zd[j], bf2f((unsigned short)v3[j]), p3);
    }
#pragma unroll
    for (int off = 8; off > 0; off >>= 1) {
      p0 += __shfl_xor(p0, off);
      p1 += __shfl_xor(p1, off);
      p2 += __shfl_xor(p2, off);
      p3 += __shfl_xor(p3, off);
    }
    if (l == 0) {
      out[c0.y] = p0;
      out[c1.y] = p1;
      out[c2.y] = p2;
      out[c3.y] = p3;
    }
  }
  for (; k < e; ++k) {
    int2 c = csr[k];
    short8 v = z8[(size_t)c.x * 16 + l];
    float p = 0.f;
#pragma unroll
    for (int j = 0; j < 8; ++j) p = fmaf(zd[j], bf2f((unsigned short)v[j]), p);
#pragma unroll
    for (int off = 8; off > 0; off >>= 1) p += __shfl_xor(p, off);
    if (l == 0) out[c.y] = p;
  }
}

extern "C" void kernel_launch(void* const* d_in, const int* in_sizes, int n_in,
                              void* d_out, int out_size, void* d_ws, size_t ws_size,
                              hipStream_t stream) {
  const float* x  = (const float*)d_in[0];
  const int*   ei = (const int*)d_in[1];
  const float* W1 = (const float*)d_in[2];
  const float* b1 = (const float*)d_in[3];
  const float* W2 = (const float*)d_in[4];
  const float* b2 = (const float*)d_in[5];

  const int N = in_sizes[0] / 128;
  const int E = in_sizes[1] / 2;
  const int* src = ei;
  const int* dst = ei + E;

  char* ws = (char*)d_ws;
  size_t off = 0;
  auto alloc = [&](size_t bytes) -> void* {
    void* p = ws + off;
    off += (bytes + 255) & ~(size_t)255;
    return p;
  };
  unsigned short* bufA = (unsigned short*)alloc((size_t)N * 128 * 2);
  unsigned short* bufB = (unsigned short*)alloc((size_t)N * 128 * 2);
  float* dinv    = (float*)alloc((size_t)N * 4);
  int*   rowptr  = (int*)alloc((size_t)(N + 1) * 4);
  int2*  csr     = (int2*)alloc((size_t)E * 8);
  short* Wp1     = (short*)alloc((size_t)2 * 8 * 4 * 64 * 8 * 2);
  short* Wp2     = (short*)alloc((size_t)2 * 8 * 4 * 64 * 8 * 2);
  int*   tmp     = (int*)alloc((size_t)N * 4);
  int*   deg     = (int*)alloc((size_t)N * 4);   // zeroed region starts here
  int*   cnt     = (int*)alloc((size_t)N * 4);
  int*   bsums   = (int*)alloc(1024);
  size_t zbytes = ((char*)bsums + 1024) - (char*)deg;
  hipMemsetAsync(deg, 0, zbytes, stream);

  const int E4B = (E + 1023) / 1024;
  const int NB = (N + 255) / 256;
  const int SB = (N + 511) / 512;

  // W packing (independent of graph prep)
  wpack_kernel<<<8, 256, 0, stream>>>(W1, Wp1);
  wpack_kernel<<<8, 256, 0, stream>>>(W2, Wp2);

  deg_kernel<<<E4B, 256, 0, stream>>>(dst, deg, E);
  scan1_kernel<<<SB, 512, 0, stream>>>(deg, tmp, bsums, N);
  scan2_kernel<<<1, 256, 0, stream>>>(bsums, SB);
  scan3_kernel<<<NB, 256, 0, stream>>>(tmp, bsums, deg, rowptr, dinv, N);
  scatter_kernel<<<E4B, 256, 0, stream>>>(src, dst, rowptr, cnt, csr, E);

  const int GB = (N + 127) / 128;
  const int AB = (N + 15) / 16;
  const int DB = (N + 15) / 16;

  // layer 1 (A = x, fp32 -> bf16 in-register)
  gemm_kernel<true><<<GB, 256, 0, stream>>>(x, Wp1, dinv, bufA, N);
  agg_kernel<<<AB, 256, 0, stream>>>(bufA, dinv, rowptr, csr, b1, bufB, 1, N);
  // layer 2 (A = z1, bf16)
  gemm_kernel<false><<<GB, 256, 0, stream>>>(bufB, Wp2, dinv, bufA, N);
  agg_kernel<<<AB, 256, 0, stream>>>(bufA, dinv, rowptr, csr, b2, bufB, 0, N);
  // decode over dst-CSR
  decode_kernel<<<DB, 256, 0, stream>>>(bufB, rowptr, csr, (float*)d_out, N);
}

// Round 3
// 354.048 us; speedup vs baseline: 1.1328x; 1.1328x over previous
//
#include <hip/hip_runtime.h>

// GCN link predictor: z1 = relu(GCNConv(x,W1,b1)); z2 = GCNConv(z1,W2,b2);
// out[e] = dot(z2[src[e]], z2[dst[e]])
// R9: full bf16 data plane, bf16 MFMA GEMM (hi/lo split for accuracy).
// R10: csr payload int2; 4 edges/thread prep. gemm 50us (W re-fetch latency).
// R11 FAILED: register-resident W + reg double-buffer -> allocator spilled to
//      scratch (VGPR=80 < 150 live), gemm 130us. Lesson: don't fight the
//      allocator with 150 named live values.
// R12: W (hi+lo, 64KB packed) staged ONCE per block into LDS; ds_read_b128
//      fragments feed MFMAs directly. m-tile x2 (32 rows/superstep) so each
//      W-fragment ds_read feeds 2 MFMAs. 256 rows/block, 8 supersteps,
//      '#pragma unroll 1' pins loop shape. LDS 64KB -> 2 blocks/CU;
//      launch_bounds(256,2) -> VGPR cap 256, natural pressure ~110.
//      (bench infra failed; never measured)
// R13: resubmit of R12 with LDS declared as short8[4096] to guarantee 16B
//      alignment for ds_read_b128 (was short[32768], 2B-aligned in theory).

typedef __attribute__((ext_vector_type(8))) short short8;  // 8 bf16 = 4 VGPRs
typedef __attribute__((ext_vector_type(4))) float f32x4;

__device__ __forceinline__ unsigned bf16_rne(float x) {
  unsigned u = __builtin_bit_cast(unsigned, x);
  return (u + 0x7FFFu + ((u >> 16) & 1u)) >> 16;
}
__device__ __forceinline__ float bf2f(unsigned short u) {
  return __builtin_bit_cast(float, ((unsigned)u) << 16);
}

// ---------- degree: 4 edges/thread ----------
__global__ __launch_bounds__(256) void deg_kernel(const int* __restrict__ dst,
                                                  int* __restrict__ deg, int E) {
  int base = blockIdx.x * 1024 + threadIdx.x;
#pragma unroll
  for (int i = 0; i < 4; ++i) {
    int e = base + i * 256;
    if (e < E) atomicAdd(&deg[dst[e]], 1);
  }
}

// ---------- block scan (512 elems/block) ----------
__global__ __launch_bounds__(512) void scan1_kernel(const int* __restrict__ in,
                                                    int* __restrict__ tmp,
                                                    int* __restrict__ bsums, int n) {
  __shared__ int sm[2][512];
  int t = threadIdx.x;
  int gid = blockIdx.x * 512 + t;
  int v = (gid < n) ? in[gid] : 0;
  int pp = 0;
  sm[0][t] = v;
  __syncthreads();
  for (int off = 1; off < 512; off <<= 1) {
    int nv = sm[pp][t];
    if (t >= off) nv += sm[pp][t - off];
    sm[pp ^ 1][t] = nv;
    pp ^= 1;
    __syncthreads();
  }
  int inc = sm[pp][t];
  if (gid < n) tmp[gid] = inc;
  if (t == 511) bsums[blockIdx.x] = inc;
}

__global__ __launch_bounds__(256) void scan2_kernel(int* bsums, int nb) {
  __shared__ int sm[2][256];
  int t = threadIdx.x;
  int v = (t < nb) ? bsums[t] : 0;
  int pp = 0;
  sm[0][t] = v;
  __syncthreads();
  for (int off = 1; off < 256; off <<= 1) {
    int nv = sm[pp][t];
    if (t >= off) nv += sm[pp][t - off];
    sm[pp ^ 1][t] = nv;
    pp ^= 1;
    __syncthreads();
  }
  int inc = sm[pp][t];
  if (t < nb) bsums[t] = inc - v;  // exclusive
}

// rowptr from scan, plus dinv = rsqrt(deg+1) fused here
__global__ __launch_bounds__(256) void scan3_kernel(const int* __restrict__ tmp,
                                                    const int* __restrict__ bsums,
                                                    const int* __restrict__ deg,
                                                    int* __restrict__ rowptr,
                                                    float* __restrict__ dinv, int n) {
  int gid = blockIdx.x * 256 + threadIdx.x;
  if (gid < n) {
    rowptr[gid + 1] = tmp[gid] + bsums[gid >> 9];
    dinv[gid] = rsqrtf((float)(deg[gid] + 1));  // +1 self loop
  }
  if (gid == 0) rowptr[0] = 0;
}

// CSR scatter: one int2 {src, eid} store per edge; 4 edges/thread for MLP.
__global__ __launch_bounds__(256) void scatter_kernel(const int* __restrict__ src,
                                                      const int* __restrict__ dst,
                                                      const int* __restrict__ rowptr,
                                                      int* __restrict__ cnt,
                                                      int2* __restrict__ csr, int E) {
  int base = blockIdx.x * 1024 + threadIdx.x;
#pragma unroll
  for (int i = 0; i < 4; ++i) {
    int e = base + i * 256;
    if (e < E) {
      int d = dst[e];
      int pos = rowptr[d] + atomicAdd(&cnt[d], 1);
      csr[pos] = make_int2(src[e], e);
    }
  }
}

// ---------- pack W[128][128] fp32 -> bf16 hi/lo in MFMA B-fragment order ----
// B frag (16x16x32): lane holds B[k=(lane>>4)*8+j][n=lane&15], j=0..7.
// Layout: Wp[half(0=hi,1=lo)][ct(8)][kf(4)][lane(64)][8] bf16.
__global__ __launch_bounds__(256) void wpack_kernel(const float* __restrict__ W,
                                                    short* __restrict__ Wp) {
  int t = blockIdx.x * 256 + threadIdx.x;  // 2048 = ct*256 + kf*64 + lane
  if (t >= 2048) return;
  int lane = t & 63;
  int kf = (t >> 6) & 3;
  int ct = t >> 8;
  int col = ct * 16 + (lane & 15);
  int k0 = kf * 32 + (lane >> 4) * 8;
  short* dh = Wp + ((((0 * 8 + ct) * 4 + kf) * 64) + lane) * 8;
  short* dl = Wp + ((((1 * 8 + ct) * 4 + kf) * 64) + lane) * 8;
  for (int j = 0; j < 8; ++j) {
    float w = W[(k0 + j) * 128 + col];
    unsigned h = bf16_rne(w);
    float hf = __builtin_bit_cast(float, h << 16);
    unsigned lo = bf16_rne(w - hf);
    dh[j] = (short)h;
    dl[j] = (short)lo;
  }
}

// ---------- bf16 MFMA GEMM: out[r,:] = bf16( dinv[r] * (A[r,:] @ W) ) ----
// FP32A=true: A is fp32, converted to bf16 in-register (layer 1, reads x).
// FP32A=false: A is bf16 (layer 2). W split hi/lo.
// Structure: packed W (64KB) staged once per block into LDS; per superstep
// (32 rows = 2 m-tiles) each W fragment is ds_read once and feeds 2 MFMAs.
// 4 waves, wave owns 2 col-tiles. 256 rows/block.
template <bool FP32A>
__global__ __launch_bounds__(256, 2) void gemm_kernel(const void* __restrict__ Av,
                                                      const short* __restrict__ Wp,
                                                      const float* __restrict__ dinv,
                                                      unsigned short* __restrict__ out,
                                                      int M) {
  __shared__ short8 lds_w[4096];  // 64 KB: [half][ct8][kf4][lane64], 16B-aligned

  const int tid = threadIdx.x;
  // stage packed W: 4096 x 16B chunks, 256 threads -> 16 iters (L2-broadcast)
  {
    const short8* Wg = (const short8*)Wp;
#pragma unroll
    for (int i = 0; i < 16; ++i) lds_w[i * 256 + tid] = Wg[i * 256 + tid];
  }
  __syncthreads();

  const int wave = tid >> 6;
  const int lane = tid & 63;
  const int quad = lane >> 4;
  const int l15 = lane & 15;
  const int colbase = wave * 32 + l15;
  const short8* WL = (const short8*)lds_w;

  const int rb0 = blockIdx.x * 256;
  const short8 s8z = {0, 0, 0, 0, 0, 0, 0, 0};

#pragma unroll 1
  for (int ss = 0; ss < 8; ++ss) {
    const int rb = rb0 + ss * 32;
    if (rb >= M) break;

    // A fragments for 2 m-tiles: lane holds A[m=l15][k=f*32+quad*8+j]
    short8 af[2][4];
#pragma unroll
    for (int mt = 0; mt < 2; ++mt) {
      const int arow = rb + mt * 16 + l15;
      const bool rok = arow < M;
      if constexpr (FP32A) {
        const float4* A4 = (const float4*)Av + (size_t)arow * 32;
#pragma unroll
        for (int f = 0; f < 4; ++f) {
          if (rok) {
            float4 a0 = A4[f * 8 + quad * 2];
            float4 a1 = A4[f * 8 + quad * 2 + 1];
            float av[8] = {a0.x, a0.y, a0.z, a0.w, a1.x, a1.y, a1.z, a1.w};
#pragma unroll
            for (int j = 0; j < 8; ++j) af[mt][f][j] = (short)bf16_rne(av[j]);
          } else {
            af[mt][f] = s8z;
          }
        }
      } else {
        const unsigned short* A2 = (const unsigned short*)Av + (size_t)arow * 128;
#pragma unroll
        for (int f = 0; f < 4; ++f)
          af[mt][f] = rok ? *(const short8*)(A2 + f * 32 + quad * 8) : s8z;
      }
    }

    f32x4 acc[2][2];
#pragma unroll
    for (int mt = 0; mt < 2; ++mt)
#pragma unroll
      for (int c = 0; c < 2; ++c) acc[mt][c] = (f32x4){0.f, 0.f, 0.f, 0.f};

#pragma unroll
    for (int kf = 0; kf < 4; ++kf) {
#pragma unroll
      for (int c = 0; c < 2; ++c) {
        const int ct = wave * 2 + c;
        short8 bh = WL[((0 * 8 + ct) * 4 + kf) * 64 + lane];
        short8 bl = WL[((1 * 8 + ct) * 4 + kf) * 64 + lane];
#pragma unroll
        for (int mt = 0; mt < 2; ++mt) {
          acc[mt][c] =
              __builtin_amdgcn_mfma_f32_16x16x32_bf16(af[mt][kf], bh, acc[mt][c], 0, 0, 0);
          acc[mt][c] =
              __builtin_amdgcn_mfma_f32_16x16x32_bf16(af[mt][kf], bl, acc[mt][c], 0, 0, 0);
        }
      }
    }

    // epilogue: C/D layout col=lane&15, row=quad*4+i
#pragma unroll
    for (int mt = 0; mt < 2; ++mt) {
      const int rbm = rb + mt * 16;
#pragma unroll
      for (int i = 0; i < 4; ++i) {
        const int r = rbm + quad * 4 + i;
        if (r < M) {
          const float d = dinv[r];
          out[(size_t)r * 128 + colbase] = (unsigned short)bf16_rne(acc[mt][0][i] * d);
          out[(size_t)r * 128 + colbase + 16] =
              (unsigned short)bf16_rne(acc[mt][1][i] * d);
        }
      }
    }
  }
}

// ---------- aggregation over prescaled bf16 rows ----------
// out[i] = bf16( dinv[i]*(xw[i] + sum_j xw[j]) + b ), fp32 accumulation.
// 16 lanes/node, one ushort8 (16B) per lane per row, neighbor unroll x4.
__global__ __launch_bounds__(256) void agg_kernel(const unsigned short* __restrict__ xw,
                                                  const float* __restrict__ dinv,
                                                  const int* __restrict__ rowptr,
                                                  const int2* __restrict__ csr,
                                                  const float* __restrict__ bias,
                                                  unsigned short* __restrict__ out,
                                                  int relu, int N) {
  int node = blockIdx.x * 16 + (threadIdx.x >> 4);
  int l = threadIdx.x & 15;
  if (node >= N) return;
  const short8* xw8 = (const short8*)xw;  // row = 16 short8 groups
  short8 sv = xw8[(size_t)node * 16 + l];
  float acc[8];
#pragma unroll
  for (int j = 0; j < 8; ++j) acc[j] = bf2f((unsigned short)sv[j]);
  int s = rowptr[node], e = rowptr[node + 1];
  int k = s;
  for (; k + 4 <= e; k += 4) {
    int j0 = csr[k].x, j1 = csr[k + 1].x, j2 = csr[k + 2].x, j3 = csr[k + 3].x;
    short8 v0 = xw8[(size_t)j0 * 16 + l];
    short8 v1 = xw8[(size_t)j1 * 16 + l];
    short8 v2 = xw8[(size_t)j2 * 16 + l];
    short8 v3 = xw8[(size_t)j3 * 16 + l];
#pragma unroll
    for (int j = 0; j < 8; ++j) {
      acc[j] += (bf2f((unsigned short)v0[j]) + bf2f((unsigned short)v1[j])) +
                (bf2f((unsigned short)v2[j]) + bf2f((unsigned short)v3[j]));
    }
  }
  for (; k < e; ++k) {
    short8 v = xw8[(size_t)csr[k].x * 16 + l];
#pragma unroll
    for (int j = 0; j < 8; ++j) acc[j] += bf2f((unsigned short)v[j]);
  }
  float di = dinv[node];
  const float4* b4 = (const float4*)bias;
  float4 bb0 = b4[l * 2], bb1 = b4[l * 2 + 1];
  float bv[8] = {bb0.x, bb0.y, bb0.z, bb0.w, bb1.x, bb1.y, bb1.z, bb1.w};
  short8 o;
#pragma unroll
  for (int j = 0; j < 8; ++j) {
    float v = fmaf(di, acc[j], bv[j]);
    if (relu) v = fmaxf(v, 0.f);
    o[j] = (short)bf16_rne(v);
  }
  ((short8*)out)[(size_t)node * 16 + l] = o;
}

// ---------- decode over dst-CSR, bf16 z2: 16 lanes/node ----------
__global__ __launch_bounds__(256) void decode_kernel(const unsigned short* __restrict__ z,
                                                     const int* __restrict__ rowptr,
                                                     const int2* __restrict__ csr,
                                                     float* __restrict__ out, int N) {
  int node = blockIdx.x * 16 + (threadIdx.x >> 4);
  int l = threadIdx.x & 15;
  if (node >= N) return;
  const short8* z8 = (const short8*)z;
  short8 zv = z8[(size_t)node * 16 + l];
  float zd[8];
#pragma unroll
  for (int j = 0; j < 8; ++j) zd[j] = bf2f((unsigned short)zv[j]);
  int s = rowptr[node], e = rowptr[node + 1];
  int k = s;
  for (; k + 4 <= e; k += 4) {
    int2 c0 = csr[k], c1 = csr[k + 1], c2 = csr[k + 2], c3 = csr[k + 3];
    short8 v0 = z8[(size_t)c0.x * 16 + l];
    short8 v1 = z8[(size_t)c1.x * 16 + l];
    short8 v2 = z8[(size_t)c2.x * 16 + l];
    short8 v3 = z8[(size_t)c3.x * 16 + l];
    float p0 = 0.f, p1 = 0.f, p2 = 0.f, p3 = 0.f;
#pragma unroll
    for (int j = 0; j < 8; ++j) {
      p0 = fmaf(zd[j], bf2f((unsigned short)v0[j]), p0);
      p1 = fmaf(zd[j], bf2f((unsigned short)v1[j]), p1);
      p2 = fmaf(zd[j], bf2f((unsigned short)v2[j]), p2);
      p3 = fmaf(zd[j], bf2f((unsigned short)v3[j]), p3);
    }
#pragma unroll
    for (int off = 8; off > 0; off >>= 1) {
      p0 += __shfl_xor(p0, off);
      p1 += __shfl_xor(p1, off);
      p2 += __shfl_xor(p2, off);
      p3 += __shfl_xor(p3, off);
    }
    if (l == 0) {
      out[c0.y] = p0;
      out[c1.y] = p1;
      out[c2.y] = p2;
      out[c3.y] = p3;
    }
  }
  for (; k < e; ++k) {
    int2 c = csr[k];
    short8 v = z8[(size_t)c.x * 16 + l];
    float p = 0.f;
#pragma unroll
    for (int j = 0; j < 8; ++j) p = fmaf(zd[j], bf2f((unsigned short)v[j]), p);
#pragma unroll
    for (int off = 8; off > 0; off >>= 1) p += __shfl_xor(p, off);
    if (l == 0) out[c.y] = p;
  }
}

extern "C" void kernel_launch(void* const* d_in, const int* in_sizes, int n_in,
                              void* d_out, int out_size, void* d_ws, size_t ws_size,
                              hipStream_t stream) {
  const float* x  = (const float*)d_in[0];
  const int*   ei = (const int*)d_in[1];
  const float* W1 = (const float*)d_in[2];
  const float* b1 = (const float*)d_in[3];
  const float* W2 = (const float*)d_in[4];
  const float* b2 = (const float*)d_in[5];

  const int N = in_sizes[0] / 128;
  const int E = in_sizes[1] / 2;
  const int* src = ei;
  const int* dst = ei + E;

  char* ws = (char*)d_ws;
  size_t off = 0;
  auto alloc = [&](size_t bytes) -> void* {
    void* p = ws + off;
    off += (bytes + 255) & ~(size_t)255;
    return p;
  };
  unsigned short* bufA = (unsigned short*)alloc((size_t)N * 128 * 2);
  unsigned short* bufB = (unsigned short*)alloc((size_t)N * 128 * 2);
  float* dinv    = (float*)alloc((size_t)N * 4);
  int*   rowptr  = (int*)alloc((size_t)(N + 1) * 4);
  int2*  csr     = (int2*)alloc((size_t)E * 8);
  short* Wp1     = (short*)alloc((size_t)2 * 8 * 4 * 64 * 8 * 2);
  short* Wp2     = (short*)alloc((size_t)2 * 8 * 4 * 64 * 8 * 2);
  int*   tmp     = (int*)alloc((size_t)N * 4);
  int*   deg     = (int*)alloc((size_t)N * 4);   // zeroed region starts here
  int*   cnt     = (int*)alloc((size_t)N * 4);
  int*   bsums   = (int*)alloc(1024);
  size_t zbytes = ((char*)bsums + 1024) - (char*)deg;
  hipMemsetAsync(deg, 0, zbytes, stream);

  const int E4B = (E + 1023) / 1024;
  const int NB = (N + 255) / 256;
  const int SB = (N + 511) / 512;

  // W packing (independent of graph prep)
  wpack_kernel<<<8, 256, 0, stream>>>(W1, Wp1);
  wpack_kernel<<<8, 256, 0, stream>>>(W2, Wp2);

  deg_kernel<<<E4B, 256, 0, stream>>>(dst, deg, E);
  scan1_kernel<<<SB, 512, 0, stream>>>(deg, tmp, bsums, N);
  scan2_kernel<<<1, 256, 0, stream>>>(bsums, SB);
  scan3_kernel<<<NB, 256, 0, stream>>>(tmp, bsums, deg, rowptr, dinv, N);
  scatter_kernel<<<E4B, 256, 0, stream>>>(src, dst, rowptr, cnt, csr, E);

  const int GB = (N + 255) / 256;
  const int AB = (N + 15) / 16;
  const int DB = (N + 15) / 16;

  // layer 1 (A = x, fp32 -> bf16 in-register)
  gemm_kernel<true><<<GB, 256, 0, stream>>>(x, Wp1, dinv, bufA, N);
  agg_kernel<<<AB, 256, 0, stream>>>(bufA, dinv, rowptr, csr, b1, bufB, 1, N);
  // layer 2 (A = z1, bf16)
  gemm_kernel<false><<<GB, 256, 0, stream>>>(bufB, Wp2, dinv, bufA, N);
  agg_kernel<<<AB, 256, 0, stream>>>(bufA, dinv, rowptr, csr, b2, bufB, 0, N);
  // decode over dst-CSR
  decode_kernel<<<DB, 256, 0, stream>>>(bufB, rowptr, csr, (float*)d_out, N);
}